// Round 4
// baseline (480.093 us; speedup 1.0000x reference)
//
#include <hip/hip_runtime.h>
#include <math.h>

#define B_    128
#define N_    1369
#define DINO_ 384
#define CLIP_ 512
#define H_    8
#define CHUNKS 24
#define CH     58    // ceil(1369/24); chunks 0..22 have 58, last has 35

// ---------------------------------------------------------------------------
// helpers (fold8/bcast8 layout verified correct in R2/R3 passes)
// ---------------------------------------------------------------------------
__device__ __forceinline__ float wave_sum(float v) {
  v += __shfl_xor(v, 1);  v += __shfl_xor(v, 2);  v += __shfl_xor(v, 4);
  v += __shfl_xor(v, 8);  v += __shfl_xor(v, 16); v += __shfl_xor(v, 32);
  return v;
}

// Reduce 8 per-lane head-partials over 64 lanes with 17 shuffles.
// Returns the full sum for head phi(lane) = bit5<<2 | bit4<<1 | bit3.
__device__ __forceinline__ float fold8(const float* v, int lane) {
  float a0, a1, a2, a3;
  {
    float t0 = __shfl_xor(v[0], 32), t1 = __shfl_xor(v[1], 32);
    float t2 = __shfl_xor(v[2], 32), t3 = __shfl_xor(v[3], 32);
    float u0 = __shfl_xor(v[4], 32), u1 = __shfl_xor(v[5], 32);
    float u2 = __shfl_xor(v[6], 32), u3 = __shfl_xor(v[7], 32);
    const bool hi = (lane & 32) != 0;
    a0 = hi ? v[4] + u0 : v[0] + t0;
    a1 = hi ? v[5] + u1 : v[1] + t1;
    a2 = hi ? v[6] + u2 : v[2] + t2;
    a3 = hi ? v[7] + u3 : v[3] + t3;
  }
  float b0, b1;
  {
    float t0 = __shfl_xor(a0, 16), t1 = __shfl_xor(a1, 16);
    float t2 = __shfl_xor(a2, 16), t3 = __shfl_xor(a3, 16);
    const bool hi = (lane & 16) != 0;
    b0 = hi ? a2 + t2 : a0 + t0;
    b1 = hi ? a3 + t3 : a1 + t1;
  }
  float c0;
  {
    float t0 = __shfl_xor(b0, 8), t1 = __shfl_xor(b1, 8);
    const bool hi = (lane & 8) != 0;
    c0 = hi ? b1 + t1 : b0 + t0;
  }
  c0 += __shfl_xor(c0, 4);
  c0 += __shfl_xor(c0, 2);
  c0 += __shfl_xor(c0, 1);
  return c0;
}

// Broadcast: every lane gets all 8 head values; P[j] = value of head phi^j.
__device__ __forceinline__ void bcast8(float p, float* P) {
  P[0] = p;
  P[1] = __shfl_xor(P[0], 8);
  P[2] = __shfl_xor(P[0], 16);
  P[3] = __shfl_xor(P[1], 16);
  P[4] = __shfl_xor(P[0], 32);
  P[5] = __shfl_xor(P[1], 32);
  P[6] = __shfl_xor(P[2], 32);
  P[7] = __shfl_xor(P[3], 32);
}

// ---------------------------------------------------------------------------
// kt: WkT[c][j] = Wk[j][c]   (384x512 -> 512x384).  grid (8,6) x 256.
// ---------------------------------------------------------------------------
__global__ __launch_bounds__(256) void kt(const float* __restrict__ Wk,
                                          float* __restrict__ WkT) {
  __shared__ float tile[64][65];
  const int tx = threadIdx.x & 63, ty = threadIdx.x >> 6;
  const int c0 = blockIdx.x * 64, j0 = blockIdx.y * 64;
  #pragma unroll
  for (int k = 0; k < 16; ++k) {
    const int jj = ty + 4 * k;
    tile[jj][tx] = Wk[(j0 + jj) * CLIP_ + c0 + tx];
  }
  __syncthreads();
  #pragma unroll
  for (int k = 0; k < 16; ++k) {
    const int cc = ty + 4 * k;
    WkT[(size_t)(c0 + cc) * DINO_ + j0 + tx] = tile[tx][cc];
  }
}

// ---------------------------------------------------------------------------
// kfront: Q[b]=clip@Wq+bq (LDS), then qk[b,h*384+j]=rs*sum_d WkT[h64+d][j]*Q
// grid 128 x 512.
// ---------------------------------------------------------------------------
__global__ __launch_bounds__(512) void kfront(const float* __restrict__ clip,
                                              const float* __restrict__ Wq,
                                              const float* __restrict__ bq,
                                              const float* __restrict__ WkT,
                                              const float* __restrict__ temp,
                                              float* __restrict__ qkout) {
  const int b = blockIdx.x, tid = threadIdx.x;
  __shared__ float cl[CLIP_];
  __shared__ float qs[CLIP_];
  cl[tid] = clip[b * CLIP_ + tid];
  __syncthreads();
  float acc = bq[tid];
  #pragma unroll 8
  for (int j = 0; j < CLIP_; ++j) acc += cl[j] * Wq[j * CLIP_ + tid];
  qs[tid] = acc;
  __syncthreads();
  const float rs = 1.0f / (8.0f * temp[0]);   // scale = sqrt(64)*temperature
  #pragma unroll
  for (int r = 0; r < 6; ++r) {
    const int e = tid + 512 * r;              // 0..3071
    const int h = e / DINO_;
    const int j = e - h * DINO_;
    float a2 = 0.0f;
    #pragma unroll 8
    for (int d = 0; d < 64; ++d)
      a2 += WkT[(size_t)(h * 64 + d) * DINO_ + j] * qs[h * 64 + d];
    qkout[(size_t)b * 3072 + e] = a2 * rs;
  }
}

// ---------------------------------------------------------------------------
// kmain: one wave per block, no LDS, no barriers. grid 3072 x 64.
// Per-lane elem map: k=0..3 -> 4*lane+k ; k=4,5 -> 256+2*lane+(k-4).
// Slot j of s[] holds head phi(lane)^j.
// ---------------------------------------------------------------------------
__global__ __launch_bounds__(64, 3) void kmain(const float* __restrict__ dino,
                                               const float* __restrict__ qk,
                                               float* __restrict__ ps,
                                               float* __restrict__ pl) {
  const int blk = blockIdx.x;
  const int b = blk / CHUNKS;
  const int c = blk - b * CHUNKS;
  const int n0 = c * CH;
  const int n1 = min(N_, n0 + CH);
  const int lane = threadIdx.x;
  const int phi = (((lane >> 5) & 1) << 2) | (((lane >> 4) & 1) << 1) | ((lane >> 3) & 1);

  float qr[H_][6];
  const float* qkb = qk + (size_t)b * 3072;
  #pragma unroll
  for (int h = 0; h < H_; ++h) {
    const float4 t4 = *(const float4*)(qkb + h * DINO_ + 4 * lane);
    const float2 t2 = *(const float2*)(qkb + h * DINO_ + 256 + 2 * lane);
    qr[h][0] = t4.x; qr[h][1] = t4.y; qr[h][2] = t4.z; qr[h][3] = t4.w;
    qr[h][4] = t2.x; qr[h][5] = t2.y;
  }

  float s[H_][6];
  float l = 0.0f;
  #pragma unroll
  for (int j = 0; j < H_; ++j)
    #pragma unroll
    for (int k = 0; k < 6; ++k) s[j][k] = 0.0f;

  const float* dbase = dino + (size_t)b * N_ * DINO_;

  for (int n = n0; n < n1; ++n) {
    const float* row = dbase + (size_t)n * DINO_;
    const float4 x4 = *(const float4*)(row + 4 * lane);
    const float2 x2 = *(const float2*)(row + 256 + 2 * lane);
    float v[H_];
    #pragma unroll
    for (int h = 0; h < H_; ++h)
      v[h] = qr[h][0] * x4.x + qr[h][1] * x4.y + qr[h][2] * x4.z
           + qr[h][3] * x4.w + qr[h][4] * x2.x + qr[h][5] * x2.y;
    const float p = __expf(fold8(v, lane));
    float P[H_];
    bcast8(p, P);
    l += p;
    #pragma unroll
    for (int j = 0; j < H_; ++j) {
      s[j][0] += P[j] * x4.x;  s[j][1] += P[j] * x4.y;
      s[j][2] += P[j] * x4.z;  s[j][3] += P[j] * x4.w;
      s[j][4] += P[j] * x2.x;  s[j][5] += P[j] * x2.y;
    }
  }

  float* pso = ps + (size_t)blk * 3072;
  #pragma unroll
  for (int j = 0; j < H_; ++j) {
    const int hh = phi ^ j;
    *(float4*)(pso + hh * DINO_ + 4 * lane) = make_float4(s[j][0], s[j][1], s[j][2], s[j][3]);
    *(float2*)(pso + hh * DINO_ + 256 + 2 * lane) = make_float2(s[j][4], s[j][5]);
  }
  if ((lane & 7) == 0) pl[blk * H_ + phi] = l;
}

// ---------------------------------------------------------------------------
// kback: sum 24 chunk partials, normalize, project through Wv (+bv), LN, out.
// grid 128 x 512.
// ---------------------------------------------------------------------------
__global__ __launch_bounds__(512) void kback(const float* __restrict__ ps,
                                             const float* __restrict__ pl,
                                             const float* __restrict__ Wv,
                                             const float* __restrict__ bv,
                                             const float* __restrict__ gamma,
                                             const float* __restrict__ beta,
                                             float* __restrict__ out) {
  const int b = blockIdx.x, tid = threadIdx.x;
  const int w = tid >> 6, lane = tid & 63;
  __shared__ float sfl[3072];
  __shared__ float rL[H_];

  float acc6[6];
  #pragma unroll
  for (int k = 0; k < 6; ++k) acc6[k] = 0.0f;
  const float* pb = ps + (size_t)b * CHUNKS * 3072;
  for (int cc = 0; cc < CHUNKS; ++cc) {
    #pragma unroll
    for (int k = 0; k < 6; ++k)
      acc6[k] += pb[(size_t)cc * 3072 + tid + 512 * k];
  }
  if (tid < H_) {
    float L = 0.0f;
    #pragma unroll
    for (int cc = 0; cc < CHUNKS; ++cc) L += pl[(b * CHUNKS + cc) * H_ + tid];
    rL[tid] = 1.0f / L;
  }
  __syncthreads();
  #pragma unroll
  for (int k = 0; k < 6; ++k) {
    const int e = tid + 512 * k;
    sfl[e] = acc6[k] * rL[e / DINO_];
  }
  __syncthreads();

  const float* srow = sfl + (tid >> 6) * DINO_;
  float acc = bv[tid];
  #pragma unroll 8
  for (int d = 0; d < DINO_; ++d) acc += srow[d] * Wv[d * CLIP_ + tid];

  float sum = wave_sum(acc);
  float sq  = wave_sum(acc * acc);
  __shared__ float rS[8], rQ[8];
  if (lane == 0) { rS[w] = sum; rQ[w] = sq; }
  __syncthreads();
  float tot = 0.0f, totq = 0.0f;
  #pragma unroll
  for (int i = 0; i < 8; ++i) { tot += rS[i]; totq += rQ[i]; }
  const float mu = tot * (1.0f / 512.0f);
  const float var = totq * (1.0f / 512.0f) - mu * mu;
  const float rstd = rsqrtf(var + 1e-5f);
  out[(size_t)b * CLIP_ + tid] = (acc - mu) * rstd * gamma[tid] + beta[tid];
}

// ---------------------------------------------------------------------------
extern "C" void kernel_launch(void* const* d_in, const int* in_sizes, int n_in,
                              void* d_out, int out_size, void* d_ws, size_t ws_size,
                              hipStream_t stream) {
  const float* dino  = (const float*)d_in[0];
  const float* clip  = (const float*)d_in[1];
  const float* Wq    = (const float*)d_in[2];
  const float* bq    = (const float*)d_in[3];
  const float* Wk    = (const float*)d_in[4];
  // d_in[5] = bk: softmax shift-invariant, dropped
  const float* Wv    = (const float*)d_in[6];
  const float* bv    = (const float*)d_in[7];
  const float* temp  = (const float*)d_in[8];
  const float* gamma = (const float*)d_in[9];
  const float* beta  = (const float*)d_in[10];
  float* out = (float*)d_out;

  float* ws  = (float*)d_ws;
  float* WkT = ws;                       // 512*384            =   196,608 f
  float* qk  = WkT + 196608;             // 128*3072           =   393,216 f
  float* ps  = qk  + 393216;             // 3072*3072          = 9,437,184 f
  float* pl  = ps  + 9437184;            // 3072*8             =    24,576 f
  // total ~40.2 MB

  kt    <<<dim3(8, 6),   256, 0, stream>>>(Wk, WkT);
  kfront<<<B_,           512, 0, stream>>>(clip, Wq, bq, WkT, temp, qk);
  kmain <<<B_ * CHUNKS,  64,  0, stream>>>(dino, qk, ps, pl);
  kback <<<B_,           512, 0, stream>>>(ps, pl, Wv, bv, gamma, beta, out);
}

// Round 5
// 478.313 us; speedup vs baseline: 1.0037x; 1.0037x over previous
//
#include <hip/hip_runtime.h>
#include <math.h>

#define B_    128
#define N_    1369
#define DINO_ 384
#define CLIP_ 512
#define H_    8
#define CHUNKS 24
#define CH     58    // ceil(1369/24); chunks 0..22 have 58, last has 35

// ---------------------------------------------------------------------------
// helpers (fold8/bcast8 layout verified correct in R2-R4 passes)
// ---------------------------------------------------------------------------
__device__ __forceinline__ float wave_sum(float v) {
  v += __shfl_xor(v, 1);  v += __shfl_xor(v, 2);  v += __shfl_xor(v, 4);
  v += __shfl_xor(v, 8);  v += __shfl_xor(v, 16); v += __shfl_xor(v, 32);
  return v;
}

// Reduce 8 per-lane head-partials over 64 lanes with 17 shuffles.
// Returns the full sum for head phi(lane) = bit5<<2 | bit4<<1 | bit3.
__device__ __forceinline__ float fold8(const float* v, int lane) {
  float a0, a1, a2, a3;
  {
    float t0 = __shfl_xor(v[0], 32), t1 = __shfl_xor(v[1], 32);
    float t2 = __shfl_xor(v[2], 32), t3 = __shfl_xor(v[3], 32);
    float u0 = __shfl_xor(v[4], 32), u1 = __shfl_xor(v[5], 32);
    float u2 = __shfl_xor(v[6], 32), u3 = __shfl_xor(v[7], 32);
    const bool hi = (lane & 32) != 0;
    a0 = hi ? v[4] + u0 : v[0] + t0;
    a1 = hi ? v[5] + u1 : v[1] + t1;
    a2 = hi ? v[6] + u2 : v[2] + t2;
    a3 = hi ? v[7] + u3 : v[3] + t3;
  }
  float b0, b1;
  {
    float t0 = __shfl_xor(a0, 16), t1 = __shfl_xor(a1, 16);
    float t2 = __shfl_xor(a2, 16), t3 = __shfl_xor(a3, 16);
    const bool hi = (lane & 16) != 0;
    b0 = hi ? a2 + t2 : a0 + t0;
    b1 = hi ? a3 + t3 : a1 + t1;
  }
  float c0;
  {
    float t0 = __shfl_xor(b0, 8), t1 = __shfl_xor(b1, 8);
    const bool hi = (lane & 8) != 0;
    c0 = hi ? b1 + t1 : b0 + t0;
  }
  c0 += __shfl_xor(c0, 4);
  c0 += __shfl_xor(c0, 2);
  c0 += __shfl_xor(c0, 1);
  return c0;
}

// Broadcast: every lane gets all 8 head values; P[j] = value of head phi^j.
__device__ __forceinline__ void bcast8(float p, float* P) {
  P[0] = p;
  P[1] = __shfl_xor(P[0], 8);
  P[2] = __shfl_xor(P[0], 16);
  P[3] = __shfl_xor(P[1], 16);
  P[4] = __shfl_xor(P[0], 32);
  P[5] = __shfl_xor(P[1], 32);
  P[6] = __shfl_xor(P[2], 32);
  P[7] = __shfl_xor(P[3], 32);
}

// ---------------------------------------------------------------------------
// kt: WkT[c][j] = Wk[j][c]   (384x512 -> 512x384).  grid (8,6) x 256.
// ---------------------------------------------------------------------------
__global__ __launch_bounds__(256) void kt(const float* __restrict__ Wk,
                                          float* __restrict__ WkT) {
  __shared__ float tile[64][65];
  const int tx = threadIdx.x & 63, ty = threadIdx.x >> 6;
  const int c0 = blockIdx.x * 64, j0 = blockIdx.y * 64;
  #pragma unroll
  for (int k = 0; k < 16; ++k) {
    const int jj = ty + 4 * k;
    tile[jj][tx] = Wk[(j0 + jj) * CLIP_ + c0 + tx];
  }
  __syncthreads();
  #pragma unroll
  for (int k = 0; k < 16; ++k) {
    const int cc = ty + 4 * k;
    WkT[(size_t)(c0 + cc) * DINO_ + j0 + tx] = tile[tx][cc];
  }
}

// ---------------------------------------------------------------------------
// kfront: Q[b]=clip@Wq+bq (LDS), then qk[b,h*384+j]=rs*sum_d WkT[h64+d][j]*Q
// grid 128 x 512.
// ---------------------------------------------------------------------------
__global__ __launch_bounds__(512) void kfront(const float* __restrict__ clip,
                                              const float* __restrict__ Wq,
                                              const float* __restrict__ bq,
                                              const float* __restrict__ WkT,
                                              const float* __restrict__ temp,
                                              float* __restrict__ qkout) {
  const int b = blockIdx.x, tid = threadIdx.x;
  __shared__ float cl[CLIP_];
  __shared__ float qs[CLIP_];
  cl[tid] = clip[b * CLIP_ + tid];
  __syncthreads();
  float acc = bq[tid];
  #pragma unroll 8
  for (int j = 0; j < CLIP_; ++j) acc += cl[j] * Wq[j * CLIP_ + tid];
  qs[tid] = acc;
  __syncthreads();
  const float rs = 1.0f / (8.0f * temp[0]);   // scale = sqrt(64)*temperature
  #pragma unroll
  for (int r = 0; r < 6; ++r) {
    const int e = tid + 512 * r;              // 0..3071
    const int h = e / DINO_;
    const int j = e - h * DINO_;
    float a2 = 0.0f;
    #pragma unroll 8
    for (int d = 0; d < 64; ++d)
      a2 += WkT[(size_t)(h * 64 + d) * DINO_ + j] * qs[h * 64 + d];
    qkout[(size_t)b * 3072 + e] = a2 * rs;
  }
}

// ---------------------------------------------------------------------------
// kmain: one wave per block, no LDS, no barriers, 2-patch ILP. grid 3072 x 64.
// Per-lane elem map: k=0..3 -> 4*lane+k ; k=4,5 -> 256+2*lane+(k-4).
// Slot j of s[] holds head phi(lane)^j.
// ---------------------------------------------------------------------------
__global__ __launch_bounds__(64, 3) void kmain(const float* __restrict__ dino,
                                               const float* __restrict__ qk,
                                               float* __restrict__ ps,
                                               float* __restrict__ pl) {
  const int blk = blockIdx.x;
  const int b = blk / CHUNKS;
  const int c = blk - b * CHUNKS;
  const int n0 = c * CH;
  const int n1 = min(N_, n0 + CH);
  const int lane = threadIdx.x;
  const int phi = (((lane >> 5) & 1) << 2) | (((lane >> 4) & 1) << 1) | ((lane >> 3) & 1);

  float qr[H_][6];
  const float* qkb = qk + (size_t)b * 3072;
  #pragma unroll
  for (int h = 0; h < H_; ++h) {
    const float4 t4 = *(const float4*)(qkb + h * DINO_ + 4 * lane);
    const float2 t2 = *(const float2*)(qkb + h * DINO_ + 256 + 2 * lane);
    qr[h][0] = t4.x; qr[h][1] = t4.y; qr[h][2] = t4.z; qr[h][3] = t4.w;
    qr[h][4] = t2.x; qr[h][5] = t2.y;
  }

  float s[H_][6];
  float l = 0.0f;
  #pragma unroll
  for (int j = 0; j < H_; ++j)
    #pragma unroll
    for (int k = 0; k < 6; ++k) s[j][k] = 0.0f;

  const float* dbase = dino + (size_t)b * N_ * DINO_;

  for (int n = n0; n < n1; n += 2) {
    const bool hb = (n + 1) < n1;               // wave-uniform
    const float* ra = dbase + (size_t)n * DINO_;
    const float* rb = dbase + (size_t)(hb ? n + 1 : n) * DINO_;
    const float4 a4 = *(const float4*)(ra + 4 * lane);
    const float2 a2 = *(const float2*)(ra + 256 + 2 * lane);
    const float4 b4 = *(const float4*)(rb + 4 * lane);
    const float2 b2 = *(const float2*)(rb + 256 + 2 * lane);

    float va[H_], vb[H_];
    #pragma unroll
    for (int h = 0; h < H_; ++h) {
      va[h] = qr[h][0] * a4.x + qr[h][1] * a4.y + qr[h][2] * a4.z
            + qr[h][3] * a4.w + qr[h][4] * a2.x + qr[h][5] * a2.y;
      vb[h] = qr[h][0] * b4.x + qr[h][1] * b4.y + qr[h][2] * b4.z
            + qr[h][3] * b4.w + qr[h][4] * b2.x + qr[h][5] * b2.y;
    }
    const float fa = fold8(va, lane);
    const float fb = fold8(vb, lane);
    const float pa = __expf(fa);
    const float pb = hb ? __expf(fb) : 0.0f;    // exact 0 kills dup row; no NaN
    float Pa[H_], Pb[H_];
    bcast8(pa, Pa);
    bcast8(pb, Pb);
    l += pa + pb;
    #pragma unroll
    for (int j = 0; j < H_; ++j) {
      s[j][0] += Pa[j] * a4.x + Pb[j] * b4.x;
      s[j][1] += Pa[j] * a4.y + Pb[j] * b4.y;
      s[j][2] += Pa[j] * a4.z + Pb[j] * b4.z;
      s[j][3] += Pa[j] * a4.w + Pb[j] * b4.w;
      s[j][4] += Pa[j] * a2.x + Pb[j] * b2.x;
      s[j][5] += Pa[j] * a2.y + Pb[j] * b2.y;
    }
  }

  float* pso = ps + (size_t)blk * 3072;
  #pragma unroll
  for (int j = 0; j < H_; ++j) {
    const int hh = phi ^ j;
    *(float4*)(pso + hh * DINO_ + 4 * lane) = make_float4(s[j][0], s[j][1], s[j][2], s[j][3]);
    *(float2*)(pso + hh * DINO_ + 256 + 2 * lane) = make_float2(s[j][4], s[j][5]);
  }
  if ((lane & 7) == 0) pl[blk * H_ + phi] = l;
}

// ---------------------------------------------------------------------------
// kback: sum 24 chunk partials, normalize, project through Wv (+bv), LN, out.
// grid 128 x 512.
// ---------------------------------------------------------------------------
__global__ __launch_bounds__(512) void kback(const float* __restrict__ ps,
                                             const float* __restrict__ pl,
                                             const float* __restrict__ Wv,
                                             const float* __restrict__ bv,
                                             const float* __restrict__ gamma,
                                             const float* __restrict__ beta,
                                             float* __restrict__ out) {
  const int b = blockIdx.x, tid = threadIdx.x;
  const int w = tid >> 6, lane = tid & 63;
  __shared__ float sfl[3072];
  __shared__ float rL[H_];

  float acc6[6];
  #pragma unroll
  for (int k = 0; k < 6; ++k) acc6[k] = 0.0f;
  const float* pb = ps + (size_t)b * CHUNKS * 3072;
  for (int cc = 0; cc < CHUNKS; ++cc) {
    #pragma unroll
    for (int k = 0; k < 6; ++k)
      acc6[k] += pb[(size_t)cc * 3072 + tid + 512 * k];
  }
  if (tid < H_) {
    float L = 0.0f;
    #pragma unroll
    for (int cc = 0; cc < CHUNKS; ++cc) L += pl[(b * CHUNKS + cc) * H_ + tid];
    rL[tid] = 1.0f / L;
  }
  __syncthreads();
  #pragma unroll
  for (int k = 0; k < 6; ++k) {
    const int e = tid + 512 * k;
    sfl[e] = acc6[k] * rL[e / DINO_];
  }
  __syncthreads();

  const float* srow = sfl + (tid >> 6) * DINO_;
  float acc = bv[tid];
  #pragma unroll 8
  for (int d = 0; d < DINO_; ++d) acc += srow[d] * Wv[d * CLIP_ + tid];

  float sum = wave_sum(acc);
  float sq  = wave_sum(acc * acc);
  __shared__ float rS[8], rQ[8];
  if (lane == 0) { rS[w] = sum; rQ[w] = sq; }
  __syncthreads();
  float tot = 0.0f, totq = 0.0f;
  #pragma unroll
  for (int i = 0; i < 8; ++i) { tot += rS[i]; totq += rQ[i]; }
  const float mu = tot * (1.0f / 512.0f);
  const float var = totq * (1.0f / 512.0f) - mu * mu;
  const float rstd = rsqrtf(var + 1e-5f);
  out[(size_t)b * CLIP_ + tid] = (acc - mu) * rstd * gamma[tid] + beta[tid];
}

// ---------------------------------------------------------------------------
extern "C" void kernel_launch(void* const* d_in, const int* in_sizes, int n_in,
                              void* d_out, int out_size, void* d_ws, size_t ws_size,
                              hipStream_t stream) {
  const float* dino  = (const float*)d_in[0];
  const float* clip  = (const float*)d_in[1];
  const float* Wq    = (const float*)d_in[2];
  const float* bq    = (const float*)d_in[3];
  const float* Wk    = (const float*)d_in[4];
  // d_in[5] = bk: softmax shift-invariant, dropped
  const float* Wv    = (const float*)d_in[6];
  const float* bv    = (const float*)d_in[7];
  const float* temp  = (const float*)d_in[8];
  const float* gamma = (const float*)d_in[9];
  const float* beta  = (const float*)d_in[10];
  float* out = (float*)d_out;

  float* ws  = (float*)d_ws;
  float* WkT = ws;                       // 512*384            =   196,608 f
  float* qk  = WkT + 196608;             // 128*3072           =   393,216 f
  float* ps  = qk  + 393216;             // 3072*3072          = 9,437,184 f
  float* pl  = ps  + 9437184;            // 3072*8             =    24,576 f
  // total ~40.2 MB

  kt    <<<dim3(8, 6),   256, 0, stream>>>(Wk, WkT);
  kfront<<<B_,           512, 0, stream>>>(clip, Wq, bq, WkT, temp, qk);
  kmain <<<B_ * CHUNKS,  64,  0, stream>>>(dino, qk, ps, pl);
  kback <<<B_,           512, 0, stream>>>(ps, pl, Wv, bv, gamma, beta, out);
}